// Round 9
// baseline (5265.243 us; speedup 1.0000x reference)
//
#include <hip/hip_runtime.h>
#include <hip/hip_bf16.h>
#include <hip/hip_fp8.h>

// LightGCN forward: one-pass bucketed edge binning (fixed-capacity regions,
// row-tagged records) + 3-hop bucket-parallel SpMM (LDS row accumulation,
// fp8 x buffers with per-hop x16 scaling) + InfoNCE loss.

#define NUM_USERS 100000
#define NUM_ITEMS 50000
#define NTOT      150000
#define DIM       64
#define NNZ_C     4000000
#define BATCH     4096
#define NUM_NEG   8

#define RPB        192                    // rows per bucket
#define NBUCKET    ((NTOT + RPB - 1) / RPB)   // 782
#define CAP        5888                   // region capacity; mean 5120, sd 72 -> +10.7 sigma
#define BIN_BLOCKS 1024
#define EPB ((NNZ_C + BIN_BLOCKS - 1) / BIN_BLOCKS)   // 3907

using fp8t = __hip_fp8_e4m3;

__device__ __forceinline__ float f8dec(unsigned char b) {
    fp8t h; h.__x = (__hip_fp8_storage_t)b; return (float)h;
}
__device__ __forceinline__ unsigned char f8enc(float f) {
    fp8t h(f); return (unsigned char)h.__x;
}

// ---- x0 = fp8(concat(user_emb, item_emb)); zero loss_accum ----------------
__global__ void convert_concat(const float* __restrict__ ue, const float* __restrict__ ie,
                               unsigned char* __restrict__ x0, float* __restrict__ loss_accum) {
    int i = blockIdx.x * blockDim.x + threadIdx.x;   // quad index
    if (i == 0) loss_accum[0] = 0.0f;
    if (i >= NTOT * DIM / 4) return;
    float4 v = (i * 4 < NUM_USERS * DIM)
                   ? ((const float4*)ue)[i]
                   : ((const float4*)ie)[i - NUM_USERS * DIM / 4];
    uchar4 o;
    o.x = f8enc(v.x); o.y = f8enc(v.y); o.z = f8enc(v.z); o.w = f8enc(v.w);
    ((uchar4*)x0)[i] = o;
}

// ---- init per-bucket write cursors to fixed region bases ------------------
__global__ void init_bcur(int* __restrict__ bcur) {
    int i = blockIdx.x * blockDim.x + threadIdx.x;
    if (i < NBUCKET) bcur[i] = i * CAP;
}

// ---- one-pass bin: LDS multisplit -> run-coalesced flush into regions -----
// Record: (row_lo<<18 | col, fp32 val). Bucket-grouped, row order arbitrary.
__global__ void __launch_bounds__(256) bin_k(const int* __restrict__ rows,
                                             const int* __restrict__ cols,
                                             const float* __restrict__ vals,
                                             int* __restrict__ bcur,
                                             int2* __restrict__ brec) {
    __shared__ int2 stage[EPB];                 // 31.3 KB
    __shared__ int  pdst[EPB];                  // 15.6 KB
    __shared__ int  lh[NBUCKET], lofs[NBUCKET], gbase[NBUCKET];  // 9.4 KB
    __shared__ int  sm[256];
    int t = threadIdx.x;
    for (int i = t; i < NBUCKET; i += 256) lh[i] = 0;
    __syncthreads();
    int e0 = blockIdx.x * EPB;
    int e1 = e0 + EPB; if (e1 > NNZ_C) e1 = NNZ_C;
    #pragma unroll 4
    for (int e = e0 + t; e < e1; e += 256) atomicAdd(&lh[rows[e] / RPB], 1);
    __syncthreads();
    // local exclusive scan lh -> lofs
    {
        const int K = (NBUCKET + 255) / 256;   // 4
        int loc[4];
        int s = 0;
        for (int k = 0; k < K; ++k) {
            int i = t * K + k;
            loc[k] = (i < NBUCKET) ? lh[i] : 0;
            s += loc[k];
        }
        sm[t] = s;
        __syncthreads();
        for (int o = 1; o < 256; o <<= 1) {
            int v = (t >= o) ? sm[t - o] : 0;
            __syncthreads();
            sm[t] += v;
            __syncthreads();
        }
        int run = sm[t] - s;
        for (int k = 0; k < K; ++k) {
            int i = t * K + k;
            if (i < NBUCKET) lofs[i] = run;
            run += loc[k];
        }
    }
    __syncthreads();
    // reserve global spans in fixed regions; reset lh as placement cursor
    for (int i = t; i < NBUCKET; i += 256) {
        int c = lh[i];
        gbase[i] = c ? atomicAdd(&bcur[i], c) : 0;
        lh[i] = 0;
    }
    __syncthreads();
    // placement (bucket-sorted into LDS)
    #pragma unroll 2
    for (int e = e0 + t; e < e1; e += 256) {
        int r = rows[e];
        int b = r / RPB;
        int rank = atomicAdd(&lh[b], 1);
        int j = lofs[b] + rank;
        stage[j] = make_int2(((r - b * RPB) << 18) | cols[e], __float_as_int(vals[e]));
        pdst[j]  = gbase[b] + rank;
    }
    __syncthreads();
    // run-coalesced flush
    int cnt = e1 - e0;
    for (int j = t; j < cnt; j += 256)
        brec[pdst[j]] = stage[j];
}

// ---- bucket-parallel SpMM: workgroup owns 192 rows, LDS fp32 accumulate ---
// x is fp8 scaled by s_in; output stored fp8 scaled by 16*s_in.
__global__ void __launch_bounds__(256) spmm_b(const unsigned char* __restrict__ x,
                                              const int* __restrict__ bcur,
                                              const int2* __restrict__ brec,
                                              unsigned char* __restrict__ y) {
    __shared__ float ly[RPB * DIM];   // 48 KB
    int b = blockIdx.x, t = threadIdx.x;
    for (int i = t; i < RPB * DIM / 4; i += 256) ((float4*)ly)[i] = make_float4(0, 0, 0, 0);
    __syncthreads();
    int s = b * CAP, e = bcur[b];
    int lane = t & 63, w = t >> 6;
    for (int j = s + w * 8; j < e; j += 32) {
        int m = e - j;
        if (m >= 8) {
            int2 r[8];
            #pragma unroll
            for (int k = 0; k < 8; ++k) r[k] = brec[j + k];
            float g[8];
            #pragma unroll
            for (int k = 0; k < 8; ++k) g[k] = f8dec(x[(r[k].x & 0x3FFFF) * DIM + lane]);
            #pragma unroll
            for (int k = 0; k < 8; ++k) {
                int row = (r[k].x >> 18) & 255;
                atomicAdd(&ly[row * DIM + lane], __int_as_float(r[k].y) * g[k]);
            }
        } else {
            for (int k = 0; k < m; ++k) {
                int2 rr = brec[j + k];
                float g = f8dec(x[(rr.x & 0x3FFFF) * DIM + lane]);
                atomicAdd(&ly[((rr.x >> 18) & 255) * DIM + lane], __int_as_float(rr.y) * g);
            }
        }
    }
    __syncthreads();
    int rows = NTOT - b * RPB; if (rows > RPB) rows = RPB;
    int base4 = b * RPB * DIM / 4;
    for (int i = t; i < rows * DIM / 4; i += 256) {
        float4 v = ((const float4*)ly)[i];
        uchar4 o;
        o.x = f8enc(v.x * 16.0f); o.y = f8enc(v.y * 16.0f);
        o.z = f8enc(v.z * 16.0f); o.w = f8enc(v.w * 16.0f);
        ((uchar4*)y)[base4 + i] = o;
    }
}

// ---- InfoNCE loss; e = 0.25*(x0 + x1/16 + x2/256 + x3/4096) ---------------
__global__ void loss_k(const unsigned char* __restrict__ x0, const unsigned char* __restrict__ x1,
                       const unsigned char* __restrict__ x2, const unsigned char* __restrict__ x3,
                       const int* __restrict__ users, const int* __restrict__ items,
                       const int* __restrict__ negs, float* __restrict__ loss_accum) {
    int w    = (blockIdx.x * blockDim.x + threadIdx.x) >> 6;
    int lane = threadIdx.x & 63;
    if (w >= BATCH) return;
    auto rowv = [&](int r) -> float {
        int o = r * DIM + lane;
        return 0.25f * f8dec(x0[o]) + 0.015625f * f8dec(x1[o]) +
               9.765625e-4f * f8dec(x2[o]) + 6.103515625e-5f * f8dec(x3[o]);
    };
    float ue = rowv(users[w]);
    float ie = rowv(NUM_USERS + items[w]);
    float p = ue * ie;
    for (int o = 32; o > 0; o >>= 1) p += __shfl_xor(p, o, 64);
    float pe = expf(p);
    float ne = 0.0f;
    for (int k = 0; k < NUM_NEG; ++k) {
        float q = ue * rowv(NUM_USERS + negs[k * BATCH + w]);
        for (int o = 32; o > 0; o >>= 1) q += __shfl_xor(q, o, 64);
        ne += expf(q);
    }
    if (lane == 0) atomicAdd(loss_accum, logf((pe + ne) / pe));
}

__global__ void finalize_k(const float* __restrict__ loss_accum, float* __restrict__ out) {
    out[0] = loss_accum[0] * (1.0f / BATCH);
}

__global__ void sentinel_k(float* __restrict__ out) {
    out[0] = -1.0f;
}

extern "C" void kernel_launch(void* const* d_in, const int* in_sizes, int n_in,
                              void* d_out, int out_size, void* d_ws, size_t ws_size,
                              hipStream_t stream) {
    const float* user_emb = (const float*)d_in[0];
    const float* item_emb = (const float*)d_in[1];
    const float* A_vals   = (const float*)d_in[2];
    const int*   A_rows   = (const int*)d_in[3];
    const int*   A_cols   = (const int*)d_in[4];
    const int*   users    = (const int*)d_in[5];
    const int*   items    = (const int*)d_in[6];
    const int*   negs     = (const int*)d_in[7];
    float* out = (float*)d_out;

    char* ws = (char*)d_ws;
    size_t off = 0;
    auto carve = [&](size_t bytes) -> char* {
        char* p = ws + off;
        off = (off + bytes + 255) & ~(size_t)255;
        return p;
    };
    unsigned char* x0 = (unsigned char*)carve((size_t)NTOT * DIM);        // 9.6 MB
    unsigned char* x1 = (unsigned char*)carve((size_t)NTOT * DIM);
    unsigned char* x2 = (unsigned char*)carve((size_t)NTOT * DIM);
    unsigned char* x3 = (unsigned char*)carve((size_t)NTOT * DIM);
    int2*  brec       = (int2*)carve(((size_t)NBUCKET * CAP + 64) * 8);   // 36.9 MB
    int*   bcur       = (int*)carve((size_t)NBUCKET * 4);
    float* loss_accum = (float*)carve(256);

    if (off > ws_size) {
        sentinel_k<<<1, 1, 0, stream>>>(out);
        return;
    }

    convert_concat<<<(NTOT * DIM / 4 + 255) / 256, 256, 0, stream>>>(user_emb, item_emb, x0, loss_accum);

    // one-pass bucketed build
    init_bcur<<<(NBUCKET + 255) / 256, 256, 0, stream>>>(bcur);
    bin_k<<<BIN_BLOCKS, 256, 0, stream>>>(A_rows, A_cols, A_vals, bcur, brec);

    // 3 hops, bucket-parallel
    spmm_b<<<NBUCKET, 256, 0, stream>>>(x0, bcur, brec, x1);
    spmm_b<<<NBUCKET, 256, 0, stream>>>(x1, bcur, brec, x2);
    spmm_b<<<NBUCKET, 256, 0, stream>>>(x2, bcur, brec, x3);

    // loss
    loss_k<<<(BATCH * 64 + 255) / 256, 256, 0, stream>>>(x0, x1, x2, x3, users, items, negs, loss_accum);
    finalize_k<<<1, 1, 0, stream>>>(loss_accum, out);
}

// Round 10
// 556.018 us; speedup vs baseline: 9.4696x; 9.4696x over previous
//
#include <hip/hip_runtime.h>
#include <hip/hip_bf16.h>
#include <hip/hip_fp8.h>

// LightGCN forward: bucketed CSR build (multisplit bin + per-bucket fix) +
// 3-hop pull SpMM (wave-per-row, 16-wide unroll, fp8 x buffers w/ x16/hop
// scaling, hop 3 sliced to loss rows) + InfoNCE loss.

#define NUM_USERS 100000
#define NUM_ITEMS 50000
#define NTOT      150000
#define DIM       64
#define NNZ_C     4000000
#define BATCH     4096
#define NUM_NEG   8
#define NSLICE    (BATCH + BATCH + NUM_NEG * BATCH)   // 40960 hop-3 rows

#define RPB        192                                 // rows per bucket
#define NBUCKET    ((NTOT + RPB - 1) / RPB)            // 782
#define BIN_BLOCKS 1024
#define EDGES_PER_BIN ((NNZ_C + BIN_BLOCKS - 1) / BIN_BLOCKS)  // 3907
#define STAGE_CAP  6656    // csr_fix staging; mean 5115 -> +21 sigma

using fp8t = __hip_fp8_e4m3;

__device__ __forceinline__ float f8dec(unsigned char b) {
    fp8t h; h.__x = (__hip_fp8_storage_t)b; return (float)h;
}
__device__ __forceinline__ unsigned char f8enc(float f) {
    fp8t h(f); return (unsigned char)h.__x;
}

// ---- zero an int buffer ---------------------------------------------------
__global__ void zero_ints(int* __restrict__ a, int n) {
    int i = blockIdx.x * blockDim.x + threadIdx.x;
    if (i < n) a[i] = 0;
}

// ---- x0 = fp8(concat(user_emb, item_emb)); zero loss_accum ----------------
__global__ void convert_concat(const float* __restrict__ ue, const float* __restrict__ ie,
                               unsigned char* __restrict__ x0, float* __restrict__ loss_accum) {
    int i = blockIdx.x * blockDim.x + threadIdx.x;   // quad index
    if (i == 0) loss_accum[0] = 0.0f;
    if (i >= NTOT * DIM / 4) return;
    float4 v = (i * 4 < NUM_USERS * DIM)
                   ? ((const float4*)ue)[i]
                   : ((const float4*)ie)[i - NUM_USERS * DIM / 4];
    uchar4 o;
    o.x = f8enc(v.x); o.y = f8enc(v.y); o.z = f8enc(v.z); o.w = f8enc(v.w);
    ((uchar4*)x0)[i] = o;
}

// ---- bucket histogram: LDS sub-hist per block, one global merge -----------
__global__ void bucket_hist_k(const int* __restrict__ rows, int* __restrict__ bhist) {
    __shared__ int lh[NBUCKET];
    for (int i = threadIdx.x; i < NBUCKET; i += blockDim.x) lh[i] = 0;
    __syncthreads();
    int stride = gridDim.x * blockDim.x;
    #pragma unroll 4
    for (int e = blockIdx.x * blockDim.x + threadIdx.x; e < NNZ_C; e += stride)
        atomicAdd(&lh[rows[e] / RPB], 1);
    __syncthreads();
    for (int i = threadIdx.x; i < NBUCKET; i += blockDim.x)
        if (lh[i]) atomicAdd(&bhist[i], lh[i]);
}

// ---- exclusive scan over NBUCKET bucket counts (single block) -------------
__global__ void bucket_scan_k(const int* __restrict__ bhist, int* __restrict__ bbase,
                              int* __restrict__ bcur) {
    __shared__ int sm[256];
    const int K = (NBUCKET + 255) / 256;   // 4
    int t = threadIdx.x;
    int loc[8];
    int s = 0;
    for (int k = 0; k < K; ++k) {
        int i = t * K + k;
        loc[k] = (i < NBUCKET) ? bhist[i] : 0;
        s += loc[k];
    }
    sm[t] = s;
    __syncthreads();
    for (int o = 1; o < 256; o <<= 1) {
        int v = (t >= o) ? sm[t - o] : 0;
        __syncthreads();
        sm[t] += v;
        __syncthreads();
    }
    int run = sm[t] - s;   // exclusive prefix for this thread
    for (int k = 0; k < K; ++k) {
        int i = t * K + k;
        if (i < NBUCKET) { bbase[i] = run; bcur[i] = run; }
        run += loc[k];
    }
    if (t == 255) bbase[NBUCKET] = NNZ_C;
}

// ---- bin pass: LDS multisplit, then run-coalesced flush -------------------
__global__ void __launch_bounds__(256) bin_k(const int* __restrict__ rows,
                                             const int* __restrict__ cols,
                                             const float* __restrict__ vals,
                                             int* __restrict__ bcur,
                                             int2* __restrict__ brec) {
    __shared__ int2 stage[EDGES_PER_BIN];   // 31.3 KB
    __shared__ int  pdst[EDGES_PER_BIN];    // 15.6 KB
    __shared__ int  lh[NBUCKET], lofs[NBUCKET], gbase[NBUCKET];  // 9.4 KB
    __shared__ int  sm[256];
    int t = threadIdx.x;
    for (int i = t; i < NBUCKET; i += 256) lh[i] = 0;
    __syncthreads();
    int e0 = blockIdx.x * EDGES_PER_BIN;
    int e1 = e0 + EDGES_PER_BIN; if (e1 > NNZ_C) e1 = NNZ_C;
    #pragma unroll 4
    for (int e = e0 + t; e < e1; e += 256) atomicAdd(&lh[rows[e] / RPB], 1);
    __syncthreads();
    {
        const int K = (NBUCKET + 255) / 256;   // 4
        int loc[4];
        int s = 0;
        for (int k = 0; k < K; ++k) {
            int i = t * K + k;
            loc[k] = (i < NBUCKET) ? lh[i] : 0;
            s += loc[k];
        }
        sm[t] = s;
        __syncthreads();
        for (int o = 1; o < 256; o <<= 1) {
            int v = (t >= o) ? sm[t - o] : 0;
            __syncthreads();
            sm[t] += v;
            __syncthreads();
        }
        int run = sm[t] - s;
        for (int k = 0; k < K; ++k) {
            int i = t * K + k;
            if (i < NBUCKET) lofs[i] = run;
            run += loc[k];
        }
    }
    __syncthreads();
    for (int i = t; i < NBUCKET; i += 256) {
        int c = lh[i];
        gbase[i] = c ? atomicAdd(&bcur[i], c) : 0;
        lh[i] = 0;
    }
    __syncthreads();
    #pragma unroll 2
    for (int e = e0 + t; e < e1; e += 256) {
        int r = rows[e];
        int b = r / RPB;
        int rank = atomicAdd(&lh[b], 1);
        int j = lofs[b] + rank;
        stage[j] = make_int2(((r - b * RPB) << 18) | cols[e], __float_as_int(vals[e]));
        pdst[j]  = gbase[b] + rank;
    }
    __syncthreads();
    int cnt = e1 - e0;
    for (int j = t; j < cnt; j += 256)
        brec[pdst[j]] = stage[j];
}

// ---- per-bucket in-place reorder into row-sorted CSR + rp -----------------
__global__ void csr_fix_k(int2* __restrict__ brec, const int* __restrict__ bbase,
                          int* __restrict__ rp) {
    __shared__ int2 stage[STAGE_CAP];
    __shared__ int lh[RPB], lb[RPB], lc[RPB], sm[RPB];
    int b = blockIdx.x;
    int t = threadIdx.x;
    int s = bbase[b], e = bbase[b + 1];
    int cnt = e - s;
    if (t < RPB) lh[t] = 0;
    __syncthreads();
    for (int j = t; j < cnt; j += 256) {
        int2 rc = brec[s + j];
        stage[j] = rc;
        atomicAdd(&lh[(rc.x >> 18) & 255], 1);
    }
    __syncthreads();
    if (t < RPB) sm[t] = lh[t];
    __syncthreads();
    for (int o = 1; o < RPB; o <<= 1) {
        int v = 0;
        if (t < RPB && t >= o) v = sm[t - o];
        __syncthreads();
        if (t < RPB) sm[t] += v;
        __syncthreads();
    }
    if (t < RPB) {
        int ex = sm[t] - lh[t];
        lb[t] = ex;
        lc[t] = 0;
        int row = b * RPB + t;
        if (row < NTOT) rp[row] = s + ex;
        if (row == NTOT - 1) rp[NTOT] = NNZ_C;
    }
    __syncthreads();
    for (int j = t; j < cnt; j += 256) {
        int2 rc = stage[j];
        int rl = (rc.x >> 18) & 255;
        int p = s + lb[rl] + atomicAdd(&lc[rl], 1);
        brec[p] = make_int2(rc.x & 0x3FFFF, rc.y);   // final CSR record (col, val)
    }
}

// ---- pull-mode SpMM body: fp8 gathers (1 line/edge), 16-wide unroll -------
__device__ __forceinline__ float spmm_row(const unsigned char* __restrict__ x,
                                          const int2* __restrict__ cpack,
                                          int s, int e, int lane) {
    float acc[8];
    #pragma unroll
    for (int k = 0; k < 8; ++k) acc[k] = 0.0f;
    int j = s;
    for (; j + 16 <= e; j += 16) {
        int2 p[16];
        #pragma unroll
        for (int k = 0; k < 16; ++k) p[k] = cpack[j + k];
        float g[16];
        #pragma unroll
        for (int k = 0; k < 16; ++k) g[k] = f8dec(x[p[k].x * DIM + lane]);
        #pragma unroll
        for (int k = 0; k < 16; ++k) acc[k & 7] = fmaf(__int_as_float(p[k].y), g[k], acc[k & 7]);
    }
    for (; j + 4 <= e; j += 4) {
        int2 p0 = cpack[j], p1 = cpack[j + 1], p2 = cpack[j + 2], p3 = cpack[j + 3];
        float g0 = f8dec(x[p0.x * DIM + lane]);
        float g1 = f8dec(x[p1.x * DIM + lane]);
        float g2 = f8dec(x[p2.x * DIM + lane]);
        float g3 = f8dec(x[p3.x * DIM + lane]);
        acc[0] = fmaf(__int_as_float(p0.y), g0, acc[0]);
        acc[1] = fmaf(__int_as_float(p1.y), g1, acc[1]);
        acc[2] = fmaf(__int_as_float(p2.y), g2, acc[2]);
        acc[3] = fmaf(__int_as_float(p3.y), g3, acc[3]);
    }
    for (; j < e; ++j) {
        int2 p = cpack[j];
        acc[0] = fmaf(__int_as_float(p.y), f8dec(x[p.x * DIM + lane]), acc[0]);
    }
    return ((acc[0] + acc[1]) + (acc[2] + acc[3])) + ((acc[4] + acc[5]) + (acc[6] + acc[7]));
}

// ---- full SpMM: one wave per row; output scaled x16 -----------------------
__global__ void spmm_k(const unsigned char* __restrict__ x, const int* __restrict__ rp,
                       const int2* __restrict__ cpack, unsigned char* __restrict__ y) {
    int row  = (blockIdx.x * blockDim.x + threadIdx.x) >> 6;
    int lane = threadIdx.x & 63;
    if (row >= NTOT) return;
    float a = spmm_row(x, cpack, rp[row], rp[row + 1], lane);
    y[row * DIM + lane] = f8enc(a * 16.0f);
}

// ---- sliced SpMM for hop 3: only rows the loss reads ----------------------
__global__ void spmm_sliced_k(const unsigned char* __restrict__ x, const int* __restrict__ rp,
                              const int2* __restrict__ cpack,
                              const int* __restrict__ users, const int* __restrict__ items,
                              const int* __restrict__ negs, unsigned char* __restrict__ y) {
    int w    = (blockIdx.x * blockDim.x + threadIdx.x) >> 6;
    int lane = threadIdx.x & 63;
    if (w >= NSLICE) return;
    int row = (w < BATCH)     ? users[w]
            : (w < 2 * BATCH) ? NUM_USERS + items[w - BATCH]
                              : NUM_USERS + negs[w - 2 * BATCH];
    float a = spmm_row(x, cpack, rp[row], rp[row + 1], lane);
    y[row * DIM + lane] = f8enc(a * 16.0f);   // duplicate rows rewrite same value: benign
}

// ---- InfoNCE loss; e = 0.25*(x0 + x1/16 + x2/256 + x3/4096) ---------------
__global__ void loss_k(const unsigned char* __restrict__ x0, const unsigned char* __restrict__ x1,
                       const unsigned char* __restrict__ x2, const unsigned char* __restrict__ x3,
                       const int* __restrict__ users, const int* __restrict__ items,
                       const int* __restrict__ negs, float* __restrict__ loss_accum) {
    int w    = (blockIdx.x * blockDim.x + threadIdx.x) >> 6;
    int lane = threadIdx.x & 63;
    if (w >= BATCH) return;
    auto rowv = [&](int r) -> float {
        int o = r * DIM + lane;
        return 0.25f * f8dec(x0[o]) + 0.015625f * f8dec(x1[o]) +
               9.765625e-4f * f8dec(x2[o]) + 6.103515625e-5f * f8dec(x3[o]);
    };
    float ue = rowv(users[w]);
    float ie = rowv(NUM_USERS + items[w]);
    float p = ue * ie;
    for (int o = 32; o > 0; o >>= 1) p += __shfl_xor(p, o, 64);
    float pe = expf(p);
    float ne = 0.0f;
    for (int k = 0; k < NUM_NEG; ++k) {
        float q = ue * rowv(NUM_USERS + negs[k * BATCH + w]);
        for (int o = 32; o > 0; o >>= 1) q += __shfl_xor(q, o, 64);
        ne += expf(q);
    }
    if (lane == 0) atomicAdd(loss_accum, logf((pe + ne) / pe));
}

__global__ void finalize_k(const float* __restrict__ loss_accum, float* __restrict__ out) {
    out[0] = loss_accum[0] * (1.0f / BATCH);
}

__global__ void sentinel_k(float* __restrict__ out) {
    out[0] = -1.0f;
}

extern "C" void kernel_launch(void* const* d_in, const int* in_sizes, int n_in,
                              void* d_out, int out_size, void* d_ws, size_t ws_size,
                              hipStream_t stream) {
    const float* user_emb = (const float*)d_in[0];
    const float* item_emb = (const float*)d_in[1];
    const float* A_vals   = (const float*)d_in[2];
    const int*   A_rows   = (const int*)d_in[3];
    const int*   A_cols   = (const int*)d_in[4];
    const int*   users    = (const int*)d_in[5];
    const int*   items    = (const int*)d_in[6];
    const int*   negs     = (const int*)d_in[7];
    float* out = (float*)d_out;

    char* ws = (char*)d_ws;
    size_t off = 0;
    auto carve = [&](size_t bytes) -> char* {
        char* p = ws + off;
        off = (off + bytes + 255) & ~(size_t)255;
        return p;
    };
    unsigned char* x0 = (unsigned char*)carve((size_t)NTOT * DIM);   // 9.6 MB
    unsigned char* x1 = (unsigned char*)carve((size_t)NTOT * DIM);
    unsigned char* x2 = (unsigned char*)carve((size_t)NTOT * DIM);
    unsigned char* x3 = (unsigned char*)carve((size_t)NTOT * DIM);
    int2*  brec       = (int2*)carve((size_t)NNZ_C * 8);             // 32 MB
    int*   rp         = (int*)carve((size_t)(NTOT + 1) * 4);
    int*   bhist      = (int*)carve((size_t)NBUCKET * 4);
    int*   bbase      = (int*)carve((size_t)(NBUCKET + 1) * 4);
    int*   bcur       = (int*)carve((size_t)NBUCKET * 4);
    float* loss_accum = (float*)carve(256);

    if (off > ws_size) {
        sentinel_k<<<1, 1, 0, stream>>>(out);
        return;
    }

    convert_concat<<<(NTOT * DIM / 4 + 255) / 256, 256, 0, stream>>>(user_emb, item_emb, x0, loss_accum);

    // bucketed CSR build
    zero_ints<<<(NBUCKET + 255) / 256, 256, 0, stream>>>(bhist, NBUCKET);
    bucket_hist_k<<<1024, 256, 0, stream>>>(A_rows, bhist);
    bucket_scan_k<<<1, 256, 0, stream>>>(bhist, bbase, bcur);
    bin_k<<<BIN_BLOCKS, 256, 0, stream>>>(A_rows, A_cols, A_vals, bcur, brec);
    csr_fix_k<<<NBUCKET, 256, 0, stream>>>(brec, bbase, rp);

    // hops 1-2 full, hop 3 sliced to loss rows
    const int spmm_blocks = (NTOT * 64 + 255) / 256;
    spmm_k<<<spmm_blocks, 256, 0, stream>>>(x0, rp, brec, x1);
    spmm_k<<<spmm_blocks, 256, 0, stream>>>(x1, rp, brec, x2);
    spmm_sliced_k<<<(NSLICE * 64 + 255) / 256, 256, 0, stream>>>(x2, rp, brec, users, items, negs, x3);

    // loss
    loss_k<<<(BATCH * 64 + 255) / 256, 256, 0, stream>>>(x0, x1, x2, x3, users, items, negs, loss_accum);
    finalize_k<<<1, 1, 0, stream>>>(loss_accum, out);
}